// Round 1
// 493.701 us; speedup vs baseline: 1.0446x; 1.0446x over previous
//
#include <hip/hip_runtime.h>
#include <hip/hip_bf16.h>
#include <stdint.h>
#include <stddef.h>

// LiteratiQuantLinear: out = x @ (sign(w)*clamp(scales,1e-8))^T
// M=8192 (4x2048), N=4096 (O), K=4096 (C), group=128 along K.
//
// R3: GEMM ported from the 128x128 2-barrier structure (910 TF = the documented
// m97-structure ceiling; vmcnt(0) drain before every barrier) to the 256x256
// deep-pipelined schedule:
//   - 4-buffer LDS ring (BK=32), staging 3 K-tiles ahead via global_load_lds
//   - counted s_waitcnt vmcnt(8) once per tile, never 0 in the main loop
//   - 2 phases/tile: {ds_read || DMA issue -> s_barrier -> lgkmcnt(0) +
//     sched_barrier(0) -> setprio(1) 16x mfma_16x16x32_bf16 setprio(0) ->
//     s_barrier}; raw s_barrier so the vmem queue survives the barrier
//   - XOR-swizzled LDS reads, inverse swizzle folded into the DMA *global*
//     source address (LDS dest linear, as global_load_lds requires)
// Prep kernel unchanged from R2.

#define M_DIM 8192
#define N_DIM 4096
#define K_DIM 4096
#define BM 256
#define BN 256
#define BK 32
#define NT (K_DIM / BK)  // 128 K-tiles

typedef __bf16 bf16x8 __attribute__((ext_vector_type(8)));
typedef float f32x4 __attribute__((ext_vector_type(4)));

__device__ __forceinline__ void async_copy16(const void* g, void* l) {
  __builtin_amdgcn_global_load_lds((__attribute__((address_space(1))) void*)g,
                                   (__attribute__((address_space(3))) void*)l,
                                   16, 0, 0);
}

// ---- fused prep: cast x -> bf16 AND w -> sign(w)*max(scale,1e-8) bf16 ----
// 16 elements per thread: 4x float4 loads, 2x 16B stores. (unchanged, R2)
#define X_THREADS ((size_t)M_DIM * K_DIM / 16)  // 2M
#define W_THREADS ((size_t)N_DIM * K_DIM / 16)  // 1M
__global__ __launch_bounds__(256) void prep_kernel(
    const float* __restrict__ x, const float* __restrict__ w,
    const float* __restrict__ scales, __bf16* __restrict__ xb,
    __bf16* __restrict__ wb) {
  const size_t t = (size_t)blockIdx.x * blockDim.x + threadIdx.x;
  if (t < X_THREADS) {
    const float4* src = (const float4*)x + t * 4;
    bf16x8* dst = (bf16x8*)xb + t * 2;
#pragma unroll
    for (int h = 0; h < 2; ++h) {
      const float4 v0 = src[h * 2 + 0];
      const float4 v1 = src[h * 2 + 1];
      bf16x8 o;
      o[0] = (__bf16)v0.x; o[1] = (__bf16)v0.y;
      o[2] = (__bf16)v0.z; o[3] = (__bf16)v0.w;
      o[4] = (__bf16)v1.x; o[5] = (__bf16)v1.y;
      o[6] = (__bf16)v1.z; o[7] = (__bf16)v1.w;
      dst[h] = o;
    }
  } else {
    const size_t u = t - X_THREADS;            // 0 .. W_THREADS-1
    const size_t idx = u * 16;                 // flat (O,C) element index
    const int o_ = (int)(idx >> 12);           // / 4096
    const int grp = (int)(idx & 4095) >> 7;    // group of 128 (16 | 128)
    const float s = fmaxf(scales[(o_ << 5) + grp], 1e-8f);
    const float4* src = (const float4*)w + u * 4;
    bf16x8* dst = (bf16x8*)wb + u * 2;
#pragma unroll
    for (int h = 0; h < 2; ++h) {
      const float4 v0 = src[h * 2 + 0];
      const float4 v1 = src[h * 2 + 1];
      bf16x8 q;
      q[0] = (__bf16)((v0.x >= 0.f) ? s : -s);
      q[1] = (__bf16)((v0.y >= 0.f) ? s : -s);
      q[2] = (__bf16)((v0.z >= 0.f) ? s : -s);
      q[3] = (__bf16)((v0.w >= 0.f) ? s : -s);
      q[4] = (__bf16)((v1.x >= 0.f) ? s : -s);
      q[5] = (__bf16)((v1.y >= 0.f) ? s : -s);
      q[6] = (__bf16)((v1.z >= 0.f) ? s : -s);
      q[7] = (__bf16)((v1.w >= 0.f) ? s : -s);
      dst[h] = q;
    }
  }
}

// ---- GEMM ----
// LDS per buffer: A 256x32 bf16 (16 KiB) + B 256x32 bf16 (16 KiB), 4 buffers.
// Slot layout (slot = 16 B = 8 bf16 of k-chunk kc, kc = k/8 in 0..3):
//   slot(r, kc) = r*4 + (kc ^ ((r>>1)&3))
// ds_read_b128 of 16 consecutive rows at fixed kc covers all 8 slot parities
// twice -> 2-way = free (m136). Staging call c64 (wave*2+i) writes slots
// [c64*64, c64*64+64) linearly: lane l -> r = c64*16 + (l>>2),
// kc = (l&3) ^ ((l>>3)&3); the swizzle is applied to the GLOBAL source addr.
//
// Pipeline: compute tile t from buf[t&3]; during tile t issue A(t+3) in
// phase 0 and B(t+3) in phase 1; vmcnt(8) before tile t's closing barrier
// guarantees tile t+1's 4 loads landed (8 newest = tiles t+2,t+3 stay in
// flight). Tail: vmcnt(4), vmcnt(0), none.

#define LDS_A(b) ((char*)lds + (b) * 32768)
#define LDS_B(b) ((char*)lds + (b) * 32768 + 16384)

#define STAGE_A(tt) do {                                              \
    char* _d = LDS_A((tt) & 3);                                       \
    async_copy16(aS[0] + (size_t)(tt) * BK, _d + dOff[0]);            \
    async_copy16(aS[1] + (size_t)(tt) * BK, _d + dOff[1]);            \
  } while (0)

#define STAGE_B(tt) do {                                              \
    char* _d = LDS_B((tt) & 3);                                       \
    async_copy16(bS[0] + (size_t)(tt) * BK, _d + dOff[0]);            \
    async_copy16(bS[1] + (size_t)(tt) * BK, _d + dOff[1]);            \
  } while (0)

#define TILE_BODY(tt, DO_STAGE, VMSTR) do {                                    \
    char* _bufA = LDS_A((tt) & 3);                                             \
    char* _bufB = LDS_B((tt) & 3);                                             \
    bf16x8 _av[4]; bf16x8 _bv[4];                                              \
    /* ---- phase 0 (m-half 0) ---- */                                         \
    _Pragma("unroll") for (int _i = 0; _i < 4; ++_i)                           \
      _av[_i] = *(const bf16x8*)(_bufA + aOff[0][_i]);                         \
    _Pragma("unroll") for (int _j = 0; _j < 4; ++_j)                           \
      _bv[_j] = *(const bf16x8*)(_bufB + bOff[_j]);                            \
    if (DO_STAGE) STAGE_A((tt) + 3);                                           \
    __builtin_amdgcn_s_barrier();                                              \
    asm volatile("s_waitcnt lgkmcnt(0)" ::: "memory");                         \
    __builtin_amdgcn_sched_barrier(0);                                         \
    __builtin_amdgcn_s_setprio(1);                                             \
    _Pragma("unroll") for (int _i = 0; _i < 4; ++_i)                           \
      _Pragma("unroll") for (int _j = 0; _j < 4; ++_j)                         \
        acc[_i][_j] = __builtin_amdgcn_mfma_f32_16x16x32_bf16(                 \
            _av[_i], _bv[_j], acc[_i][_j], 0, 0, 0);                           \
    __builtin_amdgcn_s_setprio(0);                                             \
    __builtin_amdgcn_s_barrier();                                              \
    /* ---- phase 1 (m-half 1), B-frags reused ---- */                         \
    _Pragma("unroll") for (int _i = 0; _i < 4; ++_i)                           \
      _av[_i] = *(const bf16x8*)(_bufA + aOff[1][_i]);                         \
    if (DO_STAGE) STAGE_B((tt) + 3);                                           \
    __builtin_amdgcn_s_barrier();                                              \
    asm volatile("s_waitcnt lgkmcnt(0)" ::: "memory");                         \
    __builtin_amdgcn_sched_barrier(0);                                         \
    __builtin_amdgcn_s_setprio(1);                                             \
    _Pragma("unroll") for (int _i = 0; _i < 4; ++_i)                           \
      _Pragma("unroll") for (int _j = 0; _j < 4; ++_j)                         \
        acc[4 + _i][_j] = __builtin_amdgcn_mfma_f32_16x16x32_bf16(             \
            _av[_i], _bv[_j], acc[4 + _i][_j], 0, 0, 0);                       \
    __builtin_amdgcn_s_setprio(0);                                             \
    asm volatile("s_waitcnt " VMSTR ::: "memory");                             \
    __builtin_amdgcn_s_barrier();                                              \
  } while (0)

__global__ __launch_bounds__(512, 2) void literati_gemm(
    const __bf16* __restrict__ Ab, const __bf16* __restrict__ Bb,
    float* __restrict__ C) {
  __shared__ __align__(16) char lds[4 * 32768];  // 128 KiB ring

  const int tid = threadIdx.x;
  const int lane = tid & 63;
  const int wave = tid >> 6;       // 0..7
  const int bn0 = blockIdx.x * BN;
  const int bm0 = blockIdx.y * BM;
  const int wm = wave >> 2;        // 0..1: 128-row half of the block tile
  const int wn = wave & 3;         // 0..3: 64-col quarter

  // ---- staging decomposition (per thread) ----
  const int r_in = lane >> 2;                        // 0..15 row within call
  const int kc_st = (lane & 3) ^ ((lane >> 3) & 3);  // pre-swizzled k-chunk
  const __bf16* aS[2];
  const __bf16* bS[2];
  int dOff[2];
#pragma unroll
  for (int i = 0; i < 2; ++i) {
    const int c64 = wave * 2 + i;  // 0..15: 16-row slab of the 256-row tile
    aS[i] = Ab + (size_t)(bm0 + c64 * 16 + r_in) * K_DIM + kc_st * 8;
    bS[i] = Bb + (size_t)(bn0 + c64 * 16 + r_in) * K_DIM + kc_st * 8;
    dOff[i] = (c64 * 64 + lane) * 16;  // linear LDS byte offset
  }

  // ---- fragment LDS byte offsets (16x16x32: row = lane&15, kc = lane>>4) ----
  const int fr = lane & 15;
  const int kc_rd = lane >> 4;  // 0..3
  int aOff[2][4], bOff[4];
#pragma unroll
  for (int mh = 0; mh < 2; ++mh)
#pragma unroll
    for (int i = 0; i < 4; ++i) {
      const int row = wm * 128 + mh * 64 + i * 16 + fr;
      aOff[mh][i] = (row * 4 + (kc_rd ^ ((row >> 1) & 3))) * 16;
    }
#pragma unroll
  for (int j = 0; j < 4; ++j) {
    const int row = wn * 64 + j * 16 + fr;
    bOff[j] = (row * 4 + (kc_rd ^ ((row >> 1) & 3))) * 16;
  }

  f32x4 acc[8][4];
#pragma unroll
  for (int f = 0; f < 8; ++f)
#pragma unroll
    for (int j = 0; j < 4; ++j)
#pragma unroll
      for (int r = 0; r < 4; ++r) acc[f][j][r] = 0.f;

  // ---- prologue: stage tiles 0,1,2 (12 loads/wave), wait tile 0 ----
#pragma unroll
  for (int tt = 0; tt < 3; ++tt) {
    STAGE_A(tt);
    STAGE_B(tt);
  }
  asm volatile("s_waitcnt vmcnt(8)" ::: "memory");
  __builtin_amdgcn_s_barrier();

  // ---- main loop: counted vmcnt(8), 3 tiles always in flight ----
  for (int t = 0; t < NT - 3; ++t) TILE_BODY(t, 1, "vmcnt(8)");
  // ---- tail: pipeline drains 8 -> 4 -> 0 ----
  TILE_BODY(NT - 3, 0, "vmcnt(4)");
  TILE_BODY(NT - 2, 0, "vmcnt(0)");
  TILE_BODY(NT - 1, 0, "vmcnt(0)");

  // ---- epilogue: D layout col = lane&15, row = (lane>>4)*4 + reg ----
  const int col0 = bn0 + wn * 64 + fr;
  const int rbase = bm0 + wm * 128 + (lane >> 4) * 4;
#pragma unroll
  for (int mh = 0; mh < 2; ++mh)
#pragma unroll
    for (int i = 0; i < 4; ++i) {
      const int row0 = rbase + mh * 64 + i * 16;
#pragma unroll
      for (int j = 0; j < 4; ++j) {
        float* p = C + (size_t)row0 * N_DIM + col0 + j * 16;
#pragma unroll
        for (int r = 0; r < 4; ++r)
          p[(size_t)r * N_DIM] = acc[mh * 4 + i][j][r];
      }
    }
}

extern "C" void kernel_launch(void* const* d_in, const int* in_sizes, int n_in,
                              void* d_out, int out_size, void* d_ws, size_t ws_size,
                              hipStream_t stream) {
  (void)in_sizes; (void)n_in; (void)out_size;
  const float* x = (const float*)d_in[0];      // (4,2048,4096) fp32
  const float* w = (const float*)d_in[1];      // (4096,4096) fp32
  const float* sc = (const float*)d_in[2];     // (4096,32) fp32
  float* out = (float*)d_out;                  // (4,2048,4096) fp32

  // ws layout: xb (M*K bf16) | wb (N*K bf16) = 100.7 MB; harness ws_size has
  // covered this in all prior rounds (PRECONV path was taken at 515 us).
  __bf16* xb = (__bf16*)d_ws;
  __bf16* wb = xb + (size_t)M_DIM * K_DIM;
  (void)ws_size;

  const size_t total_threads = X_THREADS + W_THREADS;  // 3M
  prep_kernel<<<(int)(total_threads / 256), 256, 0, stream>>>(x, w, sc, xb, wb);

  dim3 grid(N_DIM / BN, M_DIM / BM);  // (16, 32)
  literati_gemm<<<grid, 512, 0, stream>>>(xb, wb, out);
}

// Round 2
// 486.202 us; speedup vs baseline: 1.0607x; 1.0154x over previous
//
#include <hip/hip_runtime.h>
#include <hip/hip_bf16.h>
#include <stdint.h>
#include <stddef.h>

// LiteratiQuantLinear: out = x @ (sign(w)*clamp(scales,1e-8))^T
// M=8192 (4x2048), N=4096 (O), K=4096 (C), group=128 along K.
//
// R4: R3's counters showed cyc/tile = 2391 = MFMA(1242) + LDS-read(1152)
// exactly -- the lgkmcnt(0)+sched_barrier(0) lockstep before each MFMA
// cluster serialized the LDS and MFMA pipes. This round:
//   - ds_reads are plain loads; compiler emits fine-grained lgkmcnt(N) per
//     consuming MFMA (rule 18 applies only to inline-asm ds_read) -> waves
//     pipeline: early waves' MFMAs cover late waves' LDS reads
//   - all 12 frag reads issued at tile top (phase 1 needs no reads)
//   - main loop unrolled 4x so the LDS ring index is compile-time
//   - one sched_barrier(0) per tile at the boundary: blocks ds_reads of the
//     freshly-DMA'd buffer from hoisting between wave-local vmcnt(8) and the
//     global barrier (the only real hazard)
//   - counted vmcnt(8) (never 0 in main loop), 4-buffer ring, setprio around
//     MFMA, XOR-swizzled reads w/ inverse swizzle in DMA global src: unchanged
// Prep kernel unchanged from R2.

#define M_DIM 8192
#define N_DIM 4096
#define K_DIM 4096
#define BM 256
#define BN 256
#define BK 32
#define NT (K_DIM / BK)  // 128 K-tiles

typedef __bf16 bf16x8 __attribute__((ext_vector_type(8)));
typedef float f32x4 __attribute__((ext_vector_type(4)));

__device__ __forceinline__ void async_copy16(const void* g, void* l) {
  __builtin_amdgcn_global_load_lds((__attribute__((address_space(1))) void*)g,
                                   (__attribute__((address_space(3))) void*)l,
                                   16, 0, 0);
}

// ---- fused prep: cast x -> bf16 AND w -> sign(w)*max(scale,1e-8) bf16 ----
#define X_THREADS ((size_t)M_DIM * K_DIM / 16)  // 2M
#define W_THREADS ((size_t)N_DIM * K_DIM / 16)  // 1M
__global__ __launch_bounds__(256) void prep_kernel(
    const float* __restrict__ x, const float* __restrict__ w,
    const float* __restrict__ scales, __bf16* __restrict__ xb,
    __bf16* __restrict__ wb) {
  const size_t t = (size_t)blockIdx.x * blockDim.x + threadIdx.x;
  if (t < X_THREADS) {
    const float4* src = (const float4*)x + t * 4;
    bf16x8* dst = (bf16x8*)xb + t * 2;
#pragma unroll
    for (int h = 0; h < 2; ++h) {
      const float4 v0 = src[h * 2 + 0];
      const float4 v1 = src[h * 2 + 1];
      bf16x8 o;
      o[0] = (__bf16)v0.x; o[1] = (__bf16)v0.y;
      o[2] = (__bf16)v0.z; o[3] = (__bf16)v0.w;
      o[4] = (__bf16)v1.x; o[5] = (__bf16)v1.y;
      o[6] = (__bf16)v1.z; o[7] = (__bf16)v1.w;
      dst[h] = o;
    }
  } else {
    const size_t u = t - X_THREADS;            // 0 .. W_THREADS-1
    const size_t idx = u * 16;                 // flat (O,C) element index
    const int o_ = (int)(idx >> 12);           // / 4096
    const int grp = (int)(idx & 4095) >> 7;    // group of 128 (16 | 128)
    const float s = fmaxf(scales[(o_ << 5) + grp], 1e-8f);
    const float4* src = (const float4*)w + u * 4;
    bf16x8* dst = (bf16x8*)wb + u * 2;
#pragma unroll
    for (int h = 0; h < 2; ++h) {
      const float4 v0 = src[h * 2 + 0];
      const float4 v1 = src[h * 2 + 1];
      bf16x8 q;
      q[0] = (__bf16)((v0.x >= 0.f) ? s : -s);
      q[1] = (__bf16)((v0.y >= 0.f) ? s : -s);
      q[2] = (__bf16)((v0.z >= 0.f) ? s : -s);
      q[3] = (__bf16)((v0.w >= 0.f) ? s : -s);
      q[4] = (__bf16)((v1.x >= 0.f) ? s : -s);
      q[5] = (__bf16)((v1.y >= 0.f) ? s : -s);
      q[6] = (__bf16)((v1.z >= 0.f) ? s : -s);
      q[7] = (__bf16)((v1.w >= 0.f) ? s : -s);
      dst[h] = q;
    }
  }
}

// ---- GEMM ----
// LDS per buffer: A 256x32 bf16 (16 KiB) + B 256x32 bf16 (16 KiB), 4 buffers.
// Slot layout (slot = 16 B = 8 bf16 of k-chunk kc):
//   slot(r, kc) = r*4 + (kc ^ ((r>>1)&3))   (bank-conflict free, verified R3:
//   SQ_LDS_BANK_CONFLICT == 0)
// Staging: lane l -> linear LDS slot, pre-swizzled GLOBAL k-chunk
//   kc = (l&3) ^ ((l>>3)&3)  (inverse swizzle on source, dest linear).
// Pipeline: compute tile t from buf[t&3]; during tile t issue A(t+3) (phase 0)
// and B(t+3) (phase 1); vmcnt(8) + barrier at tile end guarantees tile t+1's
// 4 loads landed for ALL waves. Tail drains 8 -> 4 -> 0.

#define LDS_A(b) ((char*)lds + (b) * 32768)
#define LDS_B(b) ((char*)lds + (b) * 32768 + 16384)

#define STAGE_A_TO(b) do {                        \
    char* _d = LDS_A(b);                          \
    async_copy16(aP0, _d + dO0);                  \
    async_copy16(aP1, _d + dO1);                  \
  } while (0)

#define STAGE_B_TO(b) do {                        \
    char* _d = LDS_B(b);                          \
    async_copy16(bP0, _d + dO0);                  \
    async_copy16(bP1, _d + dO1);                  \
  } while (0)

#define ADVANCE do { aP0 += BK; aP1 += BK; bP0 += BK; bP1 += BK; } while (0)

// BUF is a compile-time constant 0..3. Stage target = (BUF+3)&3.
#define TILE_BODY(BUF, DO_STAGE, VMSTR) do {                                   \
    char* _bufA = LDS_A(BUF);                                                  \
    char* _bufB = LDS_B(BUF);                                                  \
    bf16x8 _av0[4], _av1[4], _bv[4];                                           \
    /* all 12 frag reads issued up front; compiler places fine lgkmcnt(N) */   \
    _Pragma("unroll") for (int _i = 0; _i < 4; ++_i)                           \
      _av0[_i] = *(const bf16x8*)(_bufA + aOff[0][_i]);                        \
    _Pragma("unroll") for (int _j = 0; _j < 4; ++_j)                           \
      _bv[_j] = *(const bf16x8*)(_bufB + bOff[_j]);                            \
    _Pragma("unroll") for (int _i = 0; _i < 4; ++_i)                           \
      _av1[_i] = *(const bf16x8*)(_bufA + aOff[1][_i]);                        \
    if (DO_STAGE) STAGE_A_TO((BUF + 3) & 3);                                   \
    __builtin_amdgcn_s_barrier();                                              \
    __builtin_amdgcn_s_setprio(1);                                             \
    _Pragma("unroll") for (int _i = 0; _i < 4; ++_i)                           \
      _Pragma("unroll") for (int _j = 0; _j < 4; ++_j)                         \
        acc[_i][_j] = __builtin_amdgcn_mfma_f32_16x16x32_bf16(                 \
            _av0[_i], _bv[_j], acc[_i][_j], 0, 0, 0);                          \
    __builtin_amdgcn_s_setprio(0);                                             \
    __builtin_amdgcn_s_barrier();                                              \
    if (DO_STAGE) { STAGE_B_TO((BUF + 3) & 3); ADVANCE; }                      \
    __builtin_amdgcn_s_barrier();                                              \
    __builtin_amdgcn_s_setprio(1);                                             \
    _Pragma("unroll") for (int _i = 0; _i < 4; ++_i)                           \
      _Pragma("unroll") for (int _j = 0; _j < 4; ++_j)                         \
        acc[4 + _i][_j] = __builtin_amdgcn_mfma_f32_16x16x32_bf16(             \
            _av1[_i], _bv[_j], acc[4 + _i][_j], 0, 0, 0);                      \
    __builtin_amdgcn_s_setprio(0);                                             \
    asm volatile("s_waitcnt " VMSTR ::: "memory");                             \
    __builtin_amdgcn_s_barrier();                                              \
    __builtin_amdgcn_sched_barrier(0); /* tile boundary: no load hoisting */   \
  } while (0)

__global__ __launch_bounds__(512, 2) void literati_gemm(
    const __bf16* __restrict__ Ab, const __bf16* __restrict__ Bb,
    float* __restrict__ C) {
  __shared__ __align__(16) char lds[4 * 32768];  // 128 KiB ring

  const int tid = threadIdx.x;
  const int lane = tid & 63;
  const int wave = tid >> 6;       // 0..7
  const int bn0 = blockIdx.x * BN;
  const int bm0 = blockIdx.y * BM;
  const int wm = wave >> 2;        // 0..1: 128-row half of the block tile
  const int wn = wave & 3;         // 0..3: 64-col quarter

  // ---- staging decomposition (per thread) ----
  const int r_in = lane >> 2;                        // 0..15 row within slab
  const int kc_st = (lane & 3) ^ ((lane >> 3) & 3);  // pre-swizzled k-chunk
  const int c0 = wave * 2;                           // slab ids c0, c0+1
  const __bf16* aP0 = Ab + (size_t)(bm0 + c0 * 16 + r_in) * K_DIM + kc_st * 8;
  const __bf16* aP1 = Ab + (size_t)(bm0 + (c0 + 1) * 16 + r_in) * K_DIM + kc_st * 8;
  const __bf16* bP0 = Bb + (size_t)(bn0 + c0 * 16 + r_in) * K_DIM + kc_st * 8;
  const __bf16* bP1 = Bb + (size_t)(bn0 + (c0 + 1) * 16 + r_in) * K_DIM + kc_st * 8;
  const int dO0 = (c0 * 64 + lane) * 16;        // linear LDS byte offsets
  const int dO1 = ((c0 + 1) * 64 + lane) * 16;

  // ---- fragment LDS byte offsets (16x16x32: row = lane&15, kc = lane>>4) ----
  const int fr = lane & 15;
  const int kc_rd = lane >> 4;  // 0..3
  int aOff[2][4], bOff[4];
#pragma unroll
  for (int mh = 0; mh < 2; ++mh)
#pragma unroll
    for (int i = 0; i < 4; ++i) {
      const int row = wm * 128 + mh * 64 + i * 16 + fr;
      aOff[mh][i] = (row * 4 + (kc_rd ^ ((row >> 1) & 3))) * 16;
    }
#pragma unroll
  for (int j = 0; j < 4; ++j) {
    const int row = wn * 64 + j * 16 + fr;
    bOff[j] = (row * 4 + (kc_rd ^ ((row >> 1) & 3))) * 16;
  }

  f32x4 acc[8][4];
#pragma unroll
  for (int f = 0; f < 8; ++f)
#pragma unroll
    for (int j = 0; j < 4; ++j)
#pragma unroll
      for (int r = 0; r < 4; ++r) acc[f][j][r] = 0.f;

  // ---- prologue: stage tiles 0,1,2 (12 loads/wave), wait tile 0 ----
  STAGE_A_TO(0); STAGE_B_TO(0); ADVANCE;
  STAGE_A_TO(1); STAGE_B_TO(1); ADVANCE;
  STAGE_A_TO(2); STAGE_B_TO(2); ADVANCE;
  asm volatile("s_waitcnt vmcnt(8)" ::: "memory");
  __builtin_amdgcn_s_barrier();
  __builtin_amdgcn_sched_barrier(0);

  // ---- main loop: 31*4 = 124 tiles, ring index compile-time ----
  for (int tq = 0; tq < 31; ++tq) {
    TILE_BODY(0, 1, "vmcnt(8)");
    TILE_BODY(1, 1, "vmcnt(8)");
    TILE_BODY(2, 1, "vmcnt(8)");
    TILE_BODY(3, 1, "vmcnt(8)");
  }
  // tile 124 (stages tile 127 into buf 3), then drain 125/126/127
  TILE_BODY(0, 1, "vmcnt(8)");
  TILE_BODY(1, 0, "vmcnt(4)");
  TILE_BODY(2, 0, "vmcnt(0)");
  TILE_BODY(3, 0, "vmcnt(0)");

  // ---- epilogue: D layout col = lane&15, row = (lane>>4)*4 + reg ----
  const int col0 = bn0 + wn * 64 + fr;
  const int rbase = bm0 + wm * 128 + (lane >> 4) * 4;
#pragma unroll
  for (int mh = 0; mh < 2; ++mh)
#pragma unroll
    for (int i = 0; i < 4; ++i) {
      const int row0 = rbase + mh * 64 + i * 16;
#pragma unroll
      for (int j = 0; j < 4; ++j) {
        float* p = C + (size_t)row0 * N_DIM + col0 + j * 16;
#pragma unroll
        for (int r = 0; r < 4; ++r)
          p[(size_t)r * N_DIM] = acc[mh * 4 + i][j][r];
      }
    }
}

extern "C" void kernel_launch(void* const* d_in, const int* in_sizes, int n_in,
                              void* d_out, int out_size, void* d_ws, size_t ws_size,
                              hipStream_t stream) {
  (void)in_sizes; (void)n_in; (void)out_size; (void)ws_size;
  const float* x = (const float*)d_in[0];      // (4,2048,4096) fp32
  const float* w = (const float*)d_in[1];      // (4096,4096) fp32
  const float* sc = (const float*)d_in[2];     // (4096,32) fp32
  float* out = (float*)d_out;                  // (4,2048,4096) fp32

  __bf16* xb = (__bf16*)d_ws;
  __bf16* wb = xb + (size_t)M_DIM * K_DIM;

  const size_t total_threads = X_THREADS + W_THREADS;  // 3M
  prep_kernel<<<(int)(total_threads / 256), 256, 0, stream>>>(x, w, sc, xb, wb);

  dim3 grid(N_DIM / BN, M_DIM / BM);  // (16, 32)
  literati_gemm<<<grid, 512, 0, stream>>>(xb, wb, out);
}